// Round 6
// baseline (452.274 us; speedup 1.0000x reference)
//
#include <hip/hip_runtime.h>
#include <math.h>

// ---------------------------------------------------------------------------
// GraphEncoder round 6: latency-shortened CSR build.
//  * kbin: CBK=4, contiguous int4 quad loads (2 vector loads replace 12
//    scalar), regs cached for write phase, no flag reads -> 1563 blocks,
//    ~24 waves/CU
//  * masked-edge detection moved into kmisc hist blocks (kflag sets bit0
//    first); kbin is pure bucket scatter
//  * NB=512 buckets of 256 nodes: kcsr 391 blocks (was 196), half work each
//  * kmisc B2 fold: k wave-uniform -> W2 row broadcast + coalesced Wt reads
// Pipeline: kinit, kflag, kmisc(prep|hist+medge), kscanb, kbin, kcsr,
//           kagg1, kgemm1, kgemm2, kagg3(list), kedgemax, kout
// ---------------------------------------------------------------------------

typedef __attribute__((ext_vector_type(8))) short short8;   // 8 bf16 = 4 VGPR
typedef __attribute__((ext_vector_type(4))) float f32x4;

#define NB 512          // buckets (dst>>8), 391 used for N=100000
#define MEDGE_CAP 262144

__device__ __forceinline__ float gelu_f(float x) {
    const float c0 = 0.7978845608028654f; // sqrt(2/pi)
    float x3 = x * x * x;
    float t = tanhf(c0 * (x + 0.044715f * x3));
    return 0.5f * x * (1.0f + t);
}
__device__ __forceinline__ unsigned short f2b(float f) {   // f32 -> bf16 RNE
    unsigned u = __float_as_uint(f);
    u += 0x7fffu + ((u >> 16) & 1);
    return (unsigned short)(u >> 16);
}
__device__ __forceinline__ float b2f(unsigned short h) {
    return __uint_as_float(((unsigned)h) << 16);
}
__device__ __forceinline__ unsigned enc_f32(float f) {     // order-preserving
    unsigned u = __float_as_uint(f);
    return (u & 0x80000000u) ? ~u : (u | 0x80000000u);
}
__device__ __forceinline__ float dec_f32(unsigned u) {
    return (u & 0x80000000u) ? __uint_as_float(u & 0x7fffffffu)
                             : __uint_as_float(~u);
}
// fragment-order position for packed weights: element (outcol c, k)
__device__ __forceinline__ int bpkpos(int c, int k) {
    int s = k >> 5, g = (k >> 3) & 3, e = k & 7, cg = c >> 4, lm = c & 15;
    return ((s * 8 + cg) * 64 + g * 16 + lm) * 8 + e;
}

// ---------------------------------------------------------------------------
// zero small region + convert x -> bf16 into A1 cols 0..63
__global__ void kinit(float4* __restrict__ z4, long n4, const float* __restrict__ x,
                      unsigned short* __restrict__ A1, int N) {
    long i = (long)blockIdx.x * blockDim.x + threadIdx.x;
    if (i < n4) { z4[i] = make_float4(0.f, 0.f, 0.f, 0.f); return; }
    long j = i - n4;
    if (j >= (long)N * 16) return;
    int node = (int)(j >> 4), c4 = (int)(j & 15);
    float4 v = *(const float4*)(x + (long)node * 64 + c4 * 4);
    ushort4 o;
    o.x = f2b(v.x); o.y = f2b(v.y); o.z = f2b(v.z); o.w = f2b(v.w);
    *(ushort4*)(A1 + (long)node * 128 + c4 * 4) = o;
}

// flag bit0 + zero masked outm rows (after kinit's zero of flag)
__global__ void kflag(const int* __restrict__ mask, int M, int* __restrict__ flag,
                      unsigned* __restrict__ outm) {
    int i = blockIdx.x * blockDim.x + threadIdx.x;
    if (i >= M) return;
    int node = mask[i];
    flag[node] = 1;
    unsigned* om = outm + (long)node * 32;
#pragma unroll
    for (int c = 0; c < 32; ++c) om[c] = 0u;
}

// ---------------------------------------------------------------------------
// fused: weight prep | bucket histogram + masked-edge detect
#define HEB 2048        // edges per hist block
__global__ __launch_bounds__(256) void kmisc(
    const float* __restrict__ W1r, const float* __restrict__ W1n,
    const float* __restrict__ W2r, const float* __restrict__ W2n,
    const float* __restrict__ b2,
    const float* __restrict__ Wts, const float* __restrict__ Wtd,
    const int* __restrict__ ei, int E,
    unsigned short* __restrict__ B1pk, unsigned short* __restrict__ B2pk,
    float* __restrict__ bc, int* __restrict__ flag,
    int* __restrict__ bcnt, int* __restrict__ nme, int* __restrict__ medge) {
    __shared__ int h[NB];
    int b = blockIdx.x, t = threadIdx.x;
    if (b < 64) {                        // B1 pack: outcol c (0..127), k (0..127)
        int idx = b * 256 + t;
        int c = idx >> 7, k = idx & 127;
        float v = (k < 64) ? W1r[k * 128 + c] : W1n[(k - 64) * 128 + c];
        B1pk[bpkpos(c, k)] = f2b(v);
    } else if (b < 128) {                // B2 fold, k wave-uniform
        int idx = (b - 64) * 256 + t;
        int c = idx & 127, k = idx >> 7;   // k: 2 values/block, uniform per half
        const float* Wrow = (c >= 64) ? (W2n + (long)k * 256) : (W2r + (long)k * 256);
        const float* Wt = ((c >> 5) & 1) ? Wtd : Wts;
        int j32 = c & 31;
        float acc = 0.f;
        for (int j = 0; j < 256; ++j) acc += Wrow[j] * Wt[j * 32 + j32];
        B2pk[bpkpos(c, k)] = f2b(acc);
    } else if (b == 128) {               // bc fold
        if (t < 64) {
            const float* Wt = ((t >> 5) & 1) ? Wtd : Wts;
            int j32 = t & 31;
            float a = 0.f;
            for (int j = 0; j < 256; ++j) a += b2[j] * Wt[j * 32 + j32];
            bc[t] = a;
        }
    } else {                             // hist + medge, HEB edges/block
        h[t] = 0; h[t + 256] = 0;
        __syncthreads();
        long base = (long)(b - 129) * HEB;
#pragma unroll
        for (int q = 0; q < HEB / 1024; ++q) {
            long e0 = base + q * 1024 + t * 4;
            if (e0 < E) {
                int4 dv = *(const int4*)&ei[E + e0];
                atomicAdd(&h[dv.x >> 8], 1);
                atomicAdd(&h[dv.y >> 8], 1);
                atomicAdd(&h[dv.z >> 8], 1);
                atomicAdd(&h[dv.w >> 8], 1);
                int f0 = flag[dv.x] & 1, f1 = flag[dv.y] & 1;
                int f2_ = flag[dv.z] & 1, f3 = flag[dv.w] & 1;
                if (f0 | f1 | f2_ | f3) {
                    int4 sv = *(const int4*)&ei[e0];
                    if (f0) { int p = atomicAdd(nme, 1); if (p < MEDGE_CAP) medge[p] = (int)e0;     atomicOr(&flag[sv.x], 2); }
                    if (f1) { int p = atomicAdd(nme, 1); if (p < MEDGE_CAP) medge[p] = (int)e0 + 1; atomicOr(&flag[sv.y], 2); }
                    if (f2_) { int p = atomicAdd(nme, 1); if (p < MEDGE_CAP) medge[p] = (int)e0 + 2; atomicOr(&flag[sv.z], 2); }
                    if (f3) { int p = atomicAdd(nme, 1); if (p < MEDGE_CAP) medge[p] = (int)e0 + 3; atomicOr(&flag[sv.w], 2); }
                }
            }
        }
        __syncthreads();
        if (h[t]) atomicAdd(&bcnt[t], h[t]);
        if (h[t + 256]) atomicAdd(&bcnt[t + 256], h[t + 256]);
    }
}

// bucket exclusive prefix (512 entries, 1 thread serial)
__global__ void kscanb(const int* __restrict__ bcnt, int* __restrict__ bstart,
                       int* __restrict__ gcur, int* __restrict__ rowptr, int N, int E) {
    if (threadIdx.x == 0 && blockIdx.x == 0) {
        int run = 0;
        for (int i = 0; i < NB; ++i) {
            bstart[i] = run; gcur[i] = run; run += bcnt[i];
        }
        rowptr[N] = run;   // == E
    }
}

// bucket scatter: 4 contiguous edges/thread, int4 loads, regs cached
__global__ __launch_bounds__(256) void kbin(const int* __restrict__ ei, int E,
        int* __restrict__ gcur, unsigned* __restrict__ bkt) {
    __shared__ int hist[NB];
    __shared__ int base_[NB];
    int t = threadIdx.x;
    long e0 = (long)blockIdx.x * 1024 + t * 4;
    hist[t] = 0; hist[t + 256] = 0;
    __syncthreads();
    int4 dv, sv;
    int lp0 = 0, lp1 = 0, lp2 = 0, lp3 = 0;
    bool ok = e0 < E;
    if (ok) {
        dv = *(const int4*)&ei[E + e0];
        sv = *(const int4*)&ei[e0];
        lp0 = atomicAdd(&hist[dv.x >> 8], 1);
        lp1 = atomicAdd(&hist[dv.y >> 8], 1);
        lp2 = atomicAdd(&hist[dv.z >> 8], 1);
        lp3 = atomicAdd(&hist[dv.w >> 8], 1);
    }
    __syncthreads();
    { int hc = hist[t]; base_[t] = hc ? atomicAdd(&gcur[t], hc) : 0; }
    { int hc = hist[t + 256]; base_[t + 256] = hc ? atomicAdd(&gcur[t + 256], hc) : 0; }
    __syncthreads();
    if (ok) {
        bkt[base_[dv.x >> 8] + lp0] = ((unsigned)(dv.x & 255) << 17) | (unsigned)sv.x;
        bkt[base_[dv.y >> 8] + lp1] = ((unsigned)(dv.y & 255) << 17) | (unsigned)sv.y;
        bkt[base_[dv.z >> 8] + lp2] = ((unsigned)(dv.z & 255) << 17) | (unsigned)sv.z;
        bkt[base_[dv.w >> 8] + lp3] = ((unsigned)(dv.w & 255) << 17) | (unsigned)sv.w;
    }
}

// per-bucket counting sort (256 nodes/bucket) -> rowptr + csr + nlist
__global__ __launch_bounds__(256) void kcsr(const unsigned* __restrict__ bkt,
        const int* __restrict__ bstart, const int* __restrict__ bcnt,
        const int* __restrict__ flag,
        int* __restrict__ rowptr, int* __restrict__ csr,
        int* __restrict__ nlist, int* __restrict__ nlcnt, int N) {
    __shared__ int hist[256];
    __shared__ int pref[256];
    __shared__ int slist[256];
    __shared__ int lcnt, lbase;
    int b = blockIdx.x, t = threadIdx.x;
    int s0 = bstart[b], cnt = bcnt[b];
    hist[t] = 0;
    if (t == 0) lcnt = 0;
    __syncthreads();
    for (int i = t; i < cnt; i += 256)
        atomicAdd(&hist[bkt[s0 + i] >> 17], 1);
    __syncthreads();
    pref[t] = hist[t];
    __syncthreads();
    for (int o = 1; o < 256; o <<= 1) {               // inclusive scan
        int v = (t >= o) ? pref[t - o] : 0;
        __syncthreads();
        pref[t] += v;
        __syncthreads();
    }
    int excl = pref[t] - hist[t];
    int n0 = (b << 8) + t;
    if (n0 < N) {
        rowptr[n0] = s0 + excl;
        if (flag[n0]) { int p = atomicAdd(&lcnt, 1); slist[p] = n0; }
    }
    __syncthreads();
    if (t == 0) lbase = atomicAdd(nlcnt, lcnt);
    pref[t] = excl;                                   // -> bucket-relative cursor
    __syncthreads();
    if (t < lcnt) nlist[lbase + t] = slist[t];
    for (int i = t; i < cnt; i += 256) {
        unsigned v = bkt[s0 + i];
        int p = atomicAdd(&pref[v >> 17], 1);
        csr[s0 + p] = (int)(v & 0x1FFFFu);
    }
}

// ---------------------------------------------------------------------------
// mean(x[src]) -> A1 cols 64..127.  8 threads per node, 16B short8 loads.
__global__ __launch_bounds__(256) void kagg1(unsigned short* __restrict__ A1,
                                             const int* __restrict__ rowptr,
                                             const int* __restrict__ csr, int N) {
    int tid = blockIdx.x * 256 + threadIdx.x;
    int n = tid >> 3, c = tid & 7;
    if (n >= N) return;
    int beg = rowptr[n], end = rowptr[n + 1];
    float acc[8] = {0.f, 0.f, 0.f, 0.f, 0.f, 0.f, 0.f, 0.f};
    int j = beg;
    for (; j + 4 <= end; j += 4) {
        int s0 = csr[j], s1 = csr[j + 1], s2 = csr[j + 2], s3 = csr[j + 3];
        short8 v0 = *(const short8*)(A1 + (long)s0 * 128 + c * 8);
        short8 v1 = *(const short8*)(A1 + (long)s1 * 128 + c * 8);
        short8 v2 = *(const short8*)(A1 + (long)s2 * 128 + c * 8);
        short8 v3 = *(const short8*)(A1 + (long)s3 * 128 + c * 8);
#pragma unroll
        for (int k = 0; k < 8; ++k)
            acc[k] += b2f((unsigned short)v0[k]) + b2f((unsigned short)v1[k])
                    + b2f((unsigned short)v2[k]) + b2f((unsigned short)v3[k]);
    }
    for (; j < end; ++j) {
        short8 v = *(const short8*)(A1 + (long)csr[j] * 128 + c * 8);
#pragma unroll
        for (int k = 0; k < 8; ++k) acc[k] += b2f((unsigned short)v[k]);
    }
    float inv = 1.f / fmaxf((float)(end - beg), 1.f);
    unsigned short o[8];
#pragma unroll
    for (int k = 0; k < 8; ++k) o[k] = f2b(acc[k] * inv);
    *(short8*)(A1 + (long)n * 128 + 64 + c * 8) = *(const short8*)o;
}

// ---------------------------------------------------------------------------
// GEMM1: h1 = gelu(A1 @ W1 + b1), K=128, cols=128. 32 rows/wave, no LDS.
__global__ __launch_bounds__(256) void kgemm1(const unsigned short* __restrict__ A1,
                                              const unsigned short* __restrict__ B1pk,
                                              const float* __restrict__ b1,
                                              unsigned short* __restrict__ h1, int N) {
    int l = threadIdx.x & 63, wv = threadIdx.x >> 6;
    int lm = l & 15, lh = l >> 4;
    long base = (long)blockIdx.x * 128 + wv * 32;
    int r0 = (int)base + lm;      if (r0 > N - 1) r0 = N - 1;
    int r1 = (int)base + 16 + lm; if (r1 > N - 1) r1 = N - 1;
    const unsigned short* a0p = A1 + (long)r0 * 128 + lh * 8;
    const unsigned short* a1p = A1 + (long)r1 * 128 + lh * 8;
    const short8* bp = (const short8*)B1pk;
    f32x4 acc[2][8];
#pragma unroll
    for (int rg = 0; rg < 2; ++rg)
#pragma unroll
        for (int cg = 0; cg < 8; ++cg) acc[rg][cg] = (f32x4){0.f, 0.f, 0.f, 0.f};
#pragma unroll
    for (int s = 0; s < 4; ++s) {
        short8 a0 = *(const short8*)(a0p + s * 32);
        short8 a1 = *(const short8*)(a1p + s * 32);
#pragma unroll
        for (int cg = 0; cg < 8; ++cg) {
            short8 b = bp[(s * 8 + cg) * 64 + l];
            acc[0][cg] = __builtin_amdgcn_mfma_f32_16x16x32_bf16(a0, b, acc[0][cg], 0, 0, 0);
            acc[1][cg] = __builtin_amdgcn_mfma_f32_16x16x32_bf16(a1, b, acc[1][cg], 0, 0, 0);
        }
    }
#pragma unroll
    for (int cg = 0; cg < 8; ++cg) {
        float bv = b1[cg * 16 + lm];
#pragma unroll
        for (int rg = 0; rg < 2; ++rg) {
#pragma unroll
            for (int r = 0; r < 4; ++r) {
                long row = base + rg * 16 + lh * 4 + r;
                if (row < N)
                    h1[row * 128 + cg * 16 + lm] = f2b(gelu_f(acc[rg][cg][r] + bv));
            }
        }
    }
}

// GEMM2: cols 0..63 -> hsd (f32, +bc) ; cols 64..127 -> z (bf16)
__global__ __launch_bounds__(256) void kgemm2(const unsigned short* __restrict__ h1,
                                              const unsigned short* __restrict__ B2pk,
                                              const float* __restrict__ bc,
                                              float* __restrict__ hsd,
                                              unsigned short* __restrict__ z, int N) {
    int l = threadIdx.x & 63, wv = threadIdx.x >> 6;
    int lm = l & 15, lh = l >> 4;
    long base = (long)blockIdx.x * 128 + wv * 32;
    int r0 = (int)base + lm;      if (r0 > N - 1) r0 = N - 1;
    int r1 = (int)base + 16 + lm; if (r1 > N - 1) r1 = N - 1;
    const unsigned short* a0p = h1 + (long)r0 * 128 + lh * 8;
    const unsigned short* a1p = h1 + (long)r1 * 128 + lh * 8;
    const short8* bp = (const short8*)B2pk;
    f32x4 acc[2][8];
#pragma unroll
    for (int rg = 0; rg < 2; ++rg)
#pragma unroll
        for (int cg = 0; cg < 8; ++cg) acc[rg][cg] = (f32x4){0.f, 0.f, 0.f, 0.f};
#pragma unroll
    for (int s = 0; s < 4; ++s) {
        short8 a0 = *(const short8*)(a0p + s * 32);
        short8 a1 = *(const short8*)(a1p + s * 32);
#pragma unroll
        for (int cg = 0; cg < 8; ++cg) {
            short8 b = bp[(s * 8 + cg) * 64 + l];
            acc[0][cg] = __builtin_amdgcn_mfma_f32_16x16x32_bf16(a0, b, acc[0][cg], 0, 0, 0);
            acc[1][cg] = __builtin_amdgcn_mfma_f32_16x16x32_bf16(a1, b, acc[1][cg], 0, 0, 0);
        }
    }
#pragma unroll
    for (int cg = 0; cg < 4; ++cg) {          // direct part
        float bv = bc[cg * 16 + lm];
#pragma unroll
        for (int rg = 0; rg < 2; ++rg)
#pragma unroll
            for (int r = 0; r < 4; ++r) {
                long row = base + rg * 16 + lh * 4 + r;
                if (row < N) hsd[row * 64 + cg * 16 + lm] = acc[rg][cg][r] + bv;
            }
    }
#pragma unroll
    for (int cg = 4; cg < 8; ++cg) {          // neighbor part -> z (bf16)
#pragma unroll
        for (int rg = 0; rg < 2; ++rg)
#pragma unroll
            for (int r = 0; r < 4; ++r) {
                long row = base + rg * 16 + lh * 4 + r;
                if (row < N) z[row * 64 + (cg - 4) * 16 + lm] = f2b(acc[rg][cg][r]);
            }
    }
}

// ---------------------------------------------------------------------------
// finalv = hsd + mean(z[src]) for LISTED nodes only.  8 threads/node.
__global__ __launch_bounds__(256) void kagg3(const unsigned short* __restrict__ z,
                                             const float* __restrict__ hsd,
                                             const int* __restrict__ rowptr,
                                             const int* __restrict__ csr,
                                             const int* __restrict__ nlist,
                                             const int* __restrict__ nlcnt,
                                             float* __restrict__ finalv) {
    int cnt = *nlcnt;
    int slots = (gridDim.x * 256) >> 3;
    int slot = (blockIdx.x * 256 + threadIdx.x) >> 3;
    int c = threadIdx.x & 7;
    for (int li = slot; li < cnt; li += slots) {
        int n = nlist[li];
        int beg = rowptr[n], end = rowptr[n + 1];
        float acc[8] = {0.f, 0.f, 0.f, 0.f, 0.f, 0.f, 0.f, 0.f};
        int j = beg;
        for (; j + 4 <= end; j += 4) {
            int s0 = csr[j], s1 = csr[j + 1], s2 = csr[j + 2], s3 = csr[j + 3];
            short8 v0 = *(const short8*)(z + (long)s0 * 64 + c * 8);
            short8 v1 = *(const short8*)(z + (long)s1 * 64 + c * 8);
            short8 v2 = *(const short8*)(z + (long)s2 * 64 + c * 8);
            short8 v3 = *(const short8*)(z + (long)s3 * 64 + c * 8);
#pragma unroll
            for (int k = 0; k < 8; ++k)
                acc[k] += b2f((unsigned short)v0[k]) + b2f((unsigned short)v1[k])
                        + b2f((unsigned short)v2[k]) + b2f((unsigned short)v3[k]);
        }
        for (; j < end; ++j) {
            short8 v = *(const short8*)(z + (long)csr[j] * 64 + c * 8);
#pragma unroll
            for (int k = 0; k < 8; ++k) acc[k] += b2f((unsigned short)v[k]);
        }
        float inv = 1.f / fmaxf((float)(end - beg), 1.f);
        float4 o0, o1;
        const float4* hp = (const float4*)(hsd + (long)n * 64 + c * 8);
        float4 h0 = hp[0], h1v = hp[1];
        o0.x = h0.x + acc[0] * inv; o0.y = h0.y + acc[1] * inv;
        o0.z = h0.z + acc[2] * inv; o0.w = h0.w + acc[3] * inv;
        o1.x = h1v.x + acc[4] * inv; o1.y = h1v.y + acc[5] * inv;
        o1.z = h1v.z + acc[6] * inv; o1.w = h1v.w + acc[7] * inv;
        float4* op = (float4*)(finalv + (long)n * 64 + c * 8);
        op[0] = o0; op[1] = o1;
    }
}

// ---------------------------------------------------------------------------
__global__ void kedgemax(const int* __restrict__ nme, const int* __restrict__ medge,
                         const int* __restrict__ ei, const float* __restrict__ et,
                         const float* __restrict__ finalv,
                         const float* __restrict__ wt, const float* __restrict__ bt,
                         unsigned* __restrict__ outm, int E) {
    int nm = *nme; if (nm > MEDGE_CAP) nm = MEDGE_CAP;
    for (int i = blockIdx.x * blockDim.x + threadIdx.x; i < nm;
         i += gridDim.x * blockDim.x) {
        int e = medge[i];
        int s = ei[e], d = ei[E + e];
        float tm = et[e];
        const float4* a4 = (const float4*)(finalv + (long)s * 64);       // hs
        const float4* b4 = (const float4*)(finalv + (long)d * 64 + 32);  // hd
        const float4* wt4 = (const float4*)wt;
        const float4* bt4 = (const float4*)bt;
        unsigned* om = outm + (long)d * 32;
#pragma unroll
        for (int c4 = 0; c4 < 8; ++c4) {
            float4 a = a4[c4], b = b4[c4], w = wt4[c4], bb = bt4[c4];
            float v0 = gelu_f(a.x + b.x + tm * w.x + bb.x);
            float v1 = gelu_f(a.y + b.y + tm * w.y + bb.y);
            float v2 = gelu_f(a.z + b.z + tm * w.z + bb.z);
            float v3 = gelu_f(a.w + b.w + tm * w.w + bb.w);
            atomicMax(om + c4 * 4 + 0, enc_f32(v0));
            atomicMax(om + c4 * 4 + 1, enc_f32(v1));
            atomicMax(om + c4 * 4 + 2, enc_f32(v2));
            atomicMax(om + c4 * 4 + 3, enc_f32(v3));
        }
    }
}

__global__ void kout(const int* __restrict__ mask, const unsigned* __restrict__ outm,
                     float* __restrict__ out, int M) {
    int idx = blockIdx.x * blockDim.x + threadIdx.x;
    if (idx >= M * 32) return;
    int i = idx >> 5, c = idx & 31;
    float f = dec_f32(outm[(long)mask[i] * 32 + c]);
    out[idx] = isfinite(f) ? f : 0.0f;
}

// ---------------------------------------------------------------------------
extern "C" void kernel_launch(void* const* d_in, const int* in_sizes, int n_in,
                              void* d_out, int out_size, void* d_ws, size_t ws_size,
                              hipStream_t stream) {
    const float* x   = (const float*)d_in[0];
    const int*   ei  = (const int*)d_in[1];
    const float* et  = (const float*)d_in[2];
    const int*   mask= (const int*)d_in[3];
    const float* W1r = (const float*)d_in[4];
    const float* W1n = (const float*)d_in[5];
    const float* b1  = (const float*)d_in[6];
    const float* W2r = (const float*)d_in[7];
    const float* W2n = (const float*)d_in[8];
    const float* b2  = (const float*)d_in[9];
    const float* Wts = (const float*)d_in[10];
    const float* Wtd = (const float*)d_in[11];
    const float* wt  = (const float*)d_in[12];
    const float* bt  = (const float*)d_in[13];

    int N = in_sizes[0] / 64;
    int E = in_sizes[1] / 2;
    int M = in_sizes[3];

    float* ws = (float*)d_ws;
    size_t off = 0;
    auto pad4 = [](size_t w) { return (w + 3) & ~(size_t)3; };
    // --- zeroed region (contiguous from ws[0]) ---
    int*      flag   = (int*)(ws + off);      off += pad4(N);
    int*      bcnt   = (int*)(ws + off);      off += NB;
    int*      nme    = (int*)(ws + off);      off += 4;
    int*      nlcnt  = (int*)(ws + off);      off += 4;
    size_t zero_words = off;
    // --- rest (not zeroed) ---
    int*      bstart = (int*)(ws + off);      off += NB;
    int*      gcur   = (int*)(ws + off);      off += NB;
    int*      rowptr = (int*)(ws + off);      off += pad4(N + 1);
    int*      csr    = (int*)(ws + off);      off += pad4(E);
    unsigned* bkt    = (unsigned*)(ws + off); off += pad4(E);
    int*      medge  = (int*)(ws + off);      off += MEDGE_CAP;
    int*      nlist  = (int*)(ws + off);      off += pad4(N);
    float*    bc     = ws + off;              off += 64;
    unsigned short* B1pk = (unsigned short*)(ws + off); off += 8192;
    unsigned short* B2pk = (unsigned short*)(ws + off); off += 8192;
    unsigned short* A1   = (unsigned short*)(ws + off); off += pad4((size_t)N * 64);
    unsigned short* h1   = (unsigned short*)(ws + off); off += pad4((size_t)N * 64);
    float*    hsd    = ws + off;              off += pad4((size_t)N * 64);
    unsigned short* zb   = (unsigned short*)(ws + off); off += pad4((size_t)N * 32);
    float*    finalv = ws + off;              off += pad4((size_t)N * 64);
    unsigned* outm   = (unsigned*)(ws + off); off += pad4((size_t)N * 32); // masked rows only

    long n4z = (long)(zero_words / 4);
    long init_total = n4z + (long)N * 16;
    int hb = (int)((E + HEB - 1) / HEB);              // hist blocks in kmisc
    int binb = (int)(((long)E + 1023) / 1024);        // kbin blocks (4 edges/thread)
    int nb_used = (N + 255) >> 8;

    kinit<<<(int)((init_total + 255) / 256), 256, 0, stream>>>(
        (float4*)ws, n4z, x, A1, N);
    kflag<<<(M + 255) / 256, 256, 0, stream>>>(mask, M, flag, outm);
    kmisc<<<129 + hb, 256, 0, stream>>>(W1r, W1n, W2r, W2n, b2, Wts, Wtd,
        ei, E, B1pk, B2pk, bc, flag, bcnt, nme, medge);
    kscanb<<<1, 64, 0, stream>>>(bcnt, bstart, gcur, rowptr, N, E);
    kbin<<<binb, 256, 0, stream>>>(ei, E, gcur, bkt);
    kcsr<<<nb_used, 256, 0, stream>>>(bkt, bstart, bcnt, flag, rowptr, csr,
                                      nlist, nlcnt, N);

    kagg1<<<(N * 8 + 255) / 256, 256, 0, stream>>>(A1, rowptr, csr, N);
    kgemm1<<<(N + 127) / 128, 256, 0, stream>>>(A1, B1pk, b1, h1, N);
    kgemm2<<<(N + 127) / 128, 256, 0, stream>>>(h1, B2pk, bc, hsd, zb, N);
    kagg3<<<512, 256, 0, stream>>>(zb, hsd, rowptr, csr, nlist, nlcnt, finalv);

    kedgemax<<<128, 256, 0, stream>>>(nme, medge, ei, et, finalv, wt, bt, outm, E);
    kout<<<(M * 32 + 255) / 256, 256, 0, stream>>>(mask, outm, (float*)d_out, M);
}